// Round 5
// baseline (30.295 us; speedup 1.0000x reference)
//
#include <hip/hip_runtime.h>
#include <math.h>

// Problem constants (from reference setup_inputs)
#define BB 16
#define QQ 900
#define NC 92
#define NCP 96          // padded LDS row
#define TT 1600
#define BQ (BB * QQ)    // 14400

// ---------------------------------------------------------------------------
// Fully fused cost kernel, full-target-sweep variant.
//   grid = (BQ/8 = 1800, 1), block = 256 = 4 waves.
//   Wave rg owns RT=2 rows; its 64 lanes sweep ALL 1600 targets (25 iters).
//   -> logits staged once per row (not 5x), 25-iter loop amortizes prologue,
//      7200 waves total = ~7 waves/SIMD, ~50 VGPR.
//   LDS: unnormalized exp(logits) [8][96] f32 = 3 KB.
//   Denominators in-wave: 32 lanes/row x 3 cols + 5x shfl_xor.
// ---------------------------------------------------------------------------
#define RT 2        // rows per thread (= rows per wave)
#define RTILE 8     // rows per block
#define NK 25       // 25 x 64 targets = 1600

__global__ __launch_bounds__(256)
void k_cost(const float* __restrict__ logits,
            const float* __restrict__ boxes,       // [BQ,4] cxcywh
            const int* __restrict__ tids,          // [TT] int32
            const float* __restrict__ tbox,        // [TT,4] cxcywh
            float* __restrict__ out) {
    __shared__ float pexp[RTILE][NCP];             // 3072 B

    const int row0 = blockIdx.x * RTILE;

    // ---- stage unnormalized exp(logit) via float2; pad cols 92..95 = 0 ----
    {   // 8*96 = 768 floats: iter0 512 floats (all threads), iter1 256 (half)
        int idx = threadIdx.x * 2;
        int r = idx / NCP, c = idx - r * NCP;      // c even
        float2 v = make_float2(0.0f, 0.0f);
        if (c < NC) {
            float2 lv = *(const float2*)&logits[(row0 + r) * NC + c];
            v.x = __expf(lv.x); v.y = __expf(lv.y);
        }
        *(float2*)&pexp[r][c] = v;
        if (threadIdx.x < 128) {
            int idx2 = 512 + threadIdx.x * 2;
            int r2 = idx2 / NCP, c2 = idx2 - r2 * NCP;
            float2 v2 = make_float2(0.0f, 0.0f);
            if (c2 < NC) {
                float2 lv = *(const float2*)&logits[(row0 + r2) * NC + c2];
                v2.x = __expf(lv.x); v2.y = __expf(lv.y);
            }
            *(float2*)&pexp[r2][c2] = v2;
        }
    }

    const int tl   = threadIdx.x & 63;
    const int rg   = threadIdx.x >> 6;
    const int rloc = rg * RT;
    const int rbase = row0 + rloc;

    // ---- register-blocked row box data ----
    float rcx[RT], rcy[RT], rw[RT], rh[RT];
    float rx0[RT], ry0[RT], rx1[RT], ry1[RT], rar[RT];
    #pragma unroll
    for (int j = 0; j < RT; ++j) {
        float4 bb = ((const float4*)boxes)[rbase + j];
        rcx[j] = bb.x; rcy[j] = bb.y; rw[j] = bb.z; rh[j] = bb.w;
        rx0[j] = bb.x - 0.5f * bb.z; ry0[j] = bb.y - 0.5f * bb.w;
        rx1[j] = bb.x + 0.5f * bb.z; ry1[j] = bb.y + 0.5f * bb.w;
        rar[j] = bb.z * bb.w;
    }
    __syncthreads();

    // ---- in-wave softmax denominators for this wave's 2 rows ----
    // lane l: row rloc + (l>>5), cols (l&31)*3 .. +2  (pad cols are 0)
    float rinv[RT];
    {
        const int lr = tl >> 5;
        const int ls = tl & 31;
        float s = pexp[rloc + lr][ls * 3]
                + pexp[rloc + lr][ls * 3 + 1]
                + pexp[rloc + lr][ls * 3 + 2];
        s += __shfl_xor(s, 1);
        s += __shfl_xor(s, 2);
        s += __shfl_xor(s, 4);
        s += __shfl_xor(s, 8);
        s += __shfl_xor(s, 16);
        rinv[0] = __builtin_amdgcn_rcpf(__shfl(s, 0));
        rinv[1] = __builtin_amdgcn_rcpf(__shfl(s, 32));
    }

    // ---- main loop: 25 x 64 targets (full sweep) ----
    float* o0 = out + rbase * TT + tl;
    #pragma unroll 5
    for (int k = 0; k < NK; ++k) {
        const int t = k * 64 + tl;
        float4 tb = ((const float4*)tbox)[t];      // cx,cy,w,h
        int    id = tids[t];
        float tx0 = tb.x - 0.5f * tb.z, ty0 = tb.y - 0.5f * tb.w;
        float tx1 = tb.x + 0.5f * tb.z, ty1 = tb.y + 0.5f * tb.w;
        float tar = tb.z * tb.w;
        #pragma unroll
        for (int j = 0; j < RT; ++j) {
            // L1 cdist in cxcywh space
            float l1 = fabsf(rcx[j] - tb.x) + fabsf(rcy[j] - tb.y)
                     + fabsf(rw[j]  - tb.z) + fabsf(rh[j]  - tb.w);
            // unclamped intersection extents
            float iwu = fminf(rx1[j], tx1) - fmaxf(rx0[j], tx0);
            float ihu = fminf(ry1[j], ty1) - fmaxf(ry0[j], ty0);
            float inter = fmaxf(iwu, 0.0f) * fmaxf(ihu, 0.0f);
            float uni = rar[j] + tar - inter;
            // enclosing box via min+max identity (always non-negative)
            float ew = (rw[j] + tb.z) - iwu;
            float eh = (rh[j] + tb.w) - ihu;
            float ea = ew * eh;
            // giou = (ea*(inter-uni) + uni^2) / (uni*ea), single rcp
            float num = fmaf(ea, inter - uni, uni * uni);
            float rden = __builtin_amdgcn_rcpf(uni * ea);
            // C = 5*l1 - prob - 2*giou
            float p = pexp[rloc + j][id];
            float c = fmaf(-p, rinv[j], 5.0f * l1);
            c = fmaf(-2.0f * num, rden, c);
            __builtin_nontemporal_store(c, o0 + j * TT + k * 64);
        }
    }
}

// ---------------------------------------------------------------------------
extern "C" void kernel_launch(void* const* d_in, const int* in_sizes, int n_in,
                              void* d_out, int out_size, void* d_ws, size_t ws_size,
                              hipStream_t stream) {
    const float* logits = (const float*)d_in[0];   // [16,900,92] f32
    const float* boxes  = (const float*)d_in[1];   // [16,900,4]  f32
    const int*   tids   = (const int*)  d_in[2];   // [1600] int32
    const float* tbox   = (const float*)d_in[3];   // [1600,4] f32
    float* out = (float*)d_out;

    k_cost<<<dim3(BQ / RTILE, 1), 256, 0, stream>>>(
        logits, boxes, tids, tbox, out);
}

// Round 6
// 28.139 us; speedup vs baseline: 1.0766x; 1.0766x over previous
//
#include <hip/hip_runtime.h>
#include <math.h>

// Problem constants (from reference setup_inputs)
#define BB 16
#define QQ 900
#define NC 92
#define NCP 96          // padded LDS row
#define TT 1600
#define BQ (BB * QQ)    // 14400

// ---------------------------------------------------------------------------
// Fully fused cost kernel. R6: plain (non-NT) stores, pre-normalized LDS
// probs, explicit next-iter prefetch. Structure identical to R5:
//   grid = (BQ/8 = 1800, 1), block = 256 = 4 waves.
//   Wave rg owns RT=2 rows; 64 lanes sweep all 1600 targets (25 iters).
//   LDS: NORMALIZED softmax probs [8][96] f32 = 3 KB (cols 92..95 = 0).
// ---------------------------------------------------------------------------
#define RT 2        // rows per thread (= rows per wave)
#define RTILE 8     // rows per block
#define NK 25       // 25 x 64 targets = 1600

__global__ __launch_bounds__(256)
void k_cost(const float* __restrict__ logits,
            const float* __restrict__ boxes,       // [BQ,4] cxcywh
            const int* __restrict__ tids,          // [TT] int32
            const float* __restrict__ tbox,        // [TT,4] cxcywh
            float* __restrict__ out) {
    __shared__ float pexp[RTILE][NCP];             // 3072 B

    const int row0 = blockIdx.x * RTILE;

    // ---- stage unnormalized exp(logit) via float2; pad cols 92..95 = 0 ----
    {   // 8*96 = 768 floats: 512 (all threads) + 256 (half)
        int idx = threadIdx.x * 2;
        int r = idx / NCP, c = idx - r * NCP;      // c even
        float2 v = make_float2(0.0f, 0.0f);
        if (c < NC) {
            float2 lv = *(const float2*)&logits[(row0 + r) * NC + c];
            v.x = __expf(lv.x); v.y = __expf(lv.y);
        }
        *(float2*)&pexp[r][c] = v;
        if (threadIdx.x < 128) {
            int idx2 = 512 + threadIdx.x * 2;
            int r2 = idx2 / NCP, c2 = idx2 - r2 * NCP;
            float2 v2 = make_float2(0.0f, 0.0f);
            if (c2 < NC) {
                float2 lv = *(const float2*)&logits[(row0 + r2) * NC + c2];
                v2.x = __expf(lv.x); v2.y = __expf(lv.y);
            }
            *(float2*)&pexp[r2][c2] = v2;
        }
    }
    __syncthreads();

    // ---- normalize LDS probs in place ----
    // thread t: row r = t>>5, slot ls = t&31 owns cols ls*3..ls*3+2
    // (stride 3 is coprime with 32 banks -> conflict-free).
    {
        const int r  = threadIdx.x >> 5;           // 0..7
        const int ls = threadIdx.x & 31;           // 0..31
        float a = pexp[r][ls * 3];
        float b = pexp[r][ls * 3 + 1];
        float d = pexp[r][ls * 3 + 2];
        float s = a + b + d;
        s += __shfl_xor(s, 1);
        s += __shfl_xor(s, 2);
        s += __shfl_xor(s, 4);
        s += __shfl_xor(s, 8);
        s += __shfl_xor(s, 16);                    // sum over the 32-lane half
        float rinv = __builtin_amdgcn_rcpf(s);
        pexp[r][ls * 3]     = a * rinv;
        pexp[r][ls * 3 + 1] = b * rinv;
        pexp[r][ls * 3 + 2] = d * rinv;
    }

    const int tl   = threadIdx.x & 63;
    const int rg   = threadIdx.x >> 6;
    const int rloc = rg * RT;
    const int rbase = row0 + rloc;

    // ---- register-blocked row box data ----
    float rcx[RT], rcy[RT], rw[RT], rh[RT];
    float rx0[RT], ry0[RT], rx1[RT], ry1[RT], rar[RT];
    #pragma unroll
    for (int j = 0; j < RT; ++j) {
        float4 bb = ((const float4*)boxes)[rbase + j];
        rcx[j] = bb.x; rcy[j] = bb.y; rw[j] = bb.z; rh[j] = bb.w;
        rx0[j] = bb.x - 0.5f * bb.z; ry0[j] = bb.y - 0.5f * bb.w;
        rx1[j] = bb.x + 0.5f * bb.z; ry1[j] = bb.y + 0.5f * bb.w;
        rar[j] = bb.z * bb.w;
    }
    __syncthreads();

    // ---- main loop: 25 x 64 targets, explicit prefetch, plain stores ----
    float* o0 = out + rbase * TT + tl;
    float4 tb = ((const float4*)tbox)[tl];
    int    id = tids[tl];
    #pragma unroll 5
    for (int k = 0; k < NK; ++k) {
        float4 tbn; int idn;
        if (k + 1 < NK) {
            tbn = ((const float4*)tbox)[(k + 1) * 64 + tl];
            idn = tids[(k + 1) * 64 + tl];
        }
        float tx0 = tb.x - 0.5f * tb.z, ty0 = tb.y - 0.5f * tb.w;
        float tx1 = tb.x + 0.5f * tb.z, ty1 = tb.y + 0.5f * tb.w;
        float tar = tb.z * tb.w;
        #pragma unroll
        for (int j = 0; j < RT; ++j) {
            // L1 cdist in cxcywh space
            float l1 = fabsf(rcx[j] - tb.x) + fabsf(rcy[j] - tb.y)
                     + fabsf(rw[j]  - tb.z) + fabsf(rh[j]  - tb.w);
            // unclamped intersection extents
            float iwu = fminf(rx1[j], tx1) - fmaxf(rx0[j], tx0);
            float ihu = fminf(ry1[j], ty1) - fmaxf(ry0[j], ty0);
            float inter = fmaxf(iwu, 0.0f) * fmaxf(ihu, 0.0f);
            float uni = rar[j] + tar - inter;
            // enclosing box via min+max identity (always non-negative)
            float ew = (rw[j] + tb.z) - iwu;
            float eh = (rh[j] + tb.w) - ihu;
            float ea = ew * eh;
            // giou = (ea*(inter-uni) + uni^2) / (uni*ea), single rcp
            float num = fmaf(ea, inter - uni, uni * uni);
            float rden = __builtin_amdgcn_rcpf(uni * ea);
            // C = 5*l1 - p - 2*giou   (p already normalized)
            float p = pexp[rloc + j][id];
            float c = fmaf(5.0f, l1, -p);
            c = fmaf(-2.0f * num, rden, c);
            o0[j * TT + k * 64] = c;
        }
        tb = tbn; id = idn;
    }
}

// ---------------------------------------------------------------------------
extern "C" void kernel_launch(void* const* d_in, const int* in_sizes, int n_in,
                              void* d_out, int out_size, void* d_ws, size_t ws_size,
                              hipStream_t stream) {
    const float* logits = (const float*)d_in[0];   // [16,900,92] f32
    const float* boxes  = (const float*)d_in[1];   // [16,900,4]  f32
    const int*   tids   = (const int*)  d_in[2];   // [1600] int32
    const float* tbox   = (const float*)d_in[3];   // [1600,4] f32
    float* out = (float*)d_out;

    k_cost<<<dim3(BQ / RTILE, 1), 256, 0, stream>>>(
        logits, boxes, tids, tbox, out);
}